// Round 4
// baseline (466.936 us; speedup 1.0000x reference)
//
#include <hip/hip_runtime.h>
#include <stdint.h>

#define HD 1024
#define SEQ 2048
#define NC 32

typedef __bf16 bf16x4 __attribute__((ext_vector_type(4)));
typedef __bf16 bf16x8 __attribute__((ext_vector_type(8)));
typedef float f32x4 __attribute__((ext_vector_type(4)));

__device__ inline unsigned short f2bf(float f) {
  union { float f; unsigned int u; } v; v.f = f;
  unsigned int r = v.u + 0x7fffu + ((v.u >> 16) & 1u);
  return (unsigned short)(r >> 16);
}
__device__ inline unsigned int pk2bf(float a, float b) {
  return (unsigned int)f2bf(a) | ((unsigned int)f2bf(b) << 16);
}
__device__ inline bf16x8 ld_frag8(const unsigned short* p) {
  bf16x4 lo = *(const bf16x4*)p;
  bf16x4 hi = *(const bf16x4*)(p + 4);
  return __builtin_shufflevector(lo, hi, 0, 1, 2, 3, 4, 5, 6, 7);
}
// async 16B global->LDS (wave-uniform base + lane*16; LDS dest stays LINEAR)
__device__ inline void glds16(const unsigned short* g, unsigned short* l) {
  __builtin_amdgcn_global_load_lds(
      (const __attribute__((address_space(1))) unsigned int*)g,
      (__attribute__((address_space(3))) unsigned int*)l, 16, 0, 0);
}
// bijective XCD swizzle: requires gridDim.x == 8 and total % 8 == 0.
__device__ inline int2 swz_bid() {
  int lin = blockIdx.y * 8 + blockIdx.x;
  int s = (lin & 7) * (int)gridDim.y + (lin >> 3);
  return make_int2(s & 7, s >> 3);
}
// ---- 128x64 bf16 tile swizzle (gemm_q): 8 col-chunks (16B) per row
__device__ inline int swz64(int row, int j) { return (row * 8 + (j ^ (row & 7))) * 8; }
// ---- 128x32 bf16 tile swizzle (gemm_kv dbuf): pair two tile-rows per 8-chunk LDS row.
// logical (row, c in 0..3) -> ldsrow = row>>1, e = ((row&1)*4 + c) ^ (ldsrow & 7)
// read offset in shorts for (row, col-chunk j):
__device__ inline int swz32(int row, int j) {
  int lr8 = row >> 1;
  return (lr8 * 8 + ((((row & 1) << 2) | j) ^ (lr8 & 7))) * 8;
}

// ---------------- zero rows s<63 of output (fallback path only) ----------------
__global__ __launch_bounds__(256) void zero_head_kernel(float* __restrict__ out) {
  int i = (blockIdx.x * 256 + threadIdx.x) * 4;
  int b = i / 64512;
  int r = i - b * 64512;
  *(float4*)(out + (size_t)b * (SEQ * HD) + r) = make_float4(0.f, 0.f, 0.f, 0.f);
}

// ---------------- merged: zero head rows + query remap/pad -> bf16 ----------------
__global__ __launch_bounds__(256) void prep_q_kernel(const float* __restrict__ q,
                                                     unsigned short* __restrict__ out,
                                                     float* __restrict__ oz) {
  int bid = blockIdx.x;
  if (bid < 252) {  // zero out[b, 0:63, :]
    int i = (bid * 256 + threadIdx.x) * 4;
    int b = i / 64512;
    int r = i - b * 64512;
    *(float4*)(oz + (size_t)b * (SEQ * HD) + r) = make_float4(0.f, 0.f, 0.f, 0.f);
    return;
  }
  int i = (bid - 252) * 256 + threadIdx.x;  // [0, 8192*128)
  int g = i >> 7, c8 = (i & 127) * 8;
  int b = g >> 11, tt = g & 2047;
  uint4 o = make_uint4(0, 0, 0, 0);
  if (tt < 1985) {
    const float* src = q + ((size_t)(b << 11) + tt + 63) * HD + c8;
    float4 a = *(const float4*)src;
    float4 bb = *(const float4*)(src + 4);
    o = make_uint4(pk2bf(a.x, a.y), pk2bf(a.z, a.w), pk2bf(bb.x, bb.y), pk2bf(bb.z, bb.w));
  }
  *(uint4*)(out + (size_t)g * HD + c8) = o;
}

// ---------------- fp32 -> bf16 streaming convert (kv tensor) ----------------
__global__ __launch_bounds__(256) void cvt_kernel(const float* __restrict__ in,
                                                  unsigned short* __restrict__ out, int n8) {
  int i = blockIdx.x * 256 + threadIdx.x;
  if (i < n8) {
    float4 a = ((const float4*)in)[(size_t)i * 2];
    float4 b = ((const float4*)in)[(size_t)i * 2 + 1];
    ((uint4*)out)[i] = make_uint4(pk2bf(a.x, a.y), pk2bf(a.z, a.w),
                                  pk2bf(b.x, b.y), pk2bf(b.z, b.w));
  }
}

// ---------------- all 3 weight matrices -> bf16 in one dispatch ----------------
__global__ __launch_bounds__(256) void cvt_w3_kernel(const float* __restrict__ Wq,
                                                     const float* __restrict__ Wk,
                                                     const float* __restrict__ Wv,
                                                     unsigned short* __restrict__ dst) {
  int bid = blockIdx.x;              // [0, 1536)
  int which = bid >> 9;              // 512 blocks per matrix
  int i = (bid & 511) * 256 + threadIdx.x;  // [0, 131072)
  const float* src = which == 0 ? Wq : (which == 1 ? Wk : Wv);
  float4 a = ((const float4*)src)[(size_t)i * 2];
  float4 b = ((const float4*)src)[(size_t)i * 2 + 1];
  ((uint4*)(dst + (size_t)which * 1048576))[i] =
      make_uint4(pk2bf(a.x, a.y), pk2bf(a.z, a.w), pk2bf(b.x, b.y), pk2bf(b.z, b.w));
}

// ---------------- Q GEMM (bf16, glds, BK=64, swizzled LDS, 2 barriers/step) ----------------
__global__ __launch_bounds__(256, 2) void gemm_q_kernel(
    const unsigned short* __restrict__ A, const unsigned short* __restrict__ W,
    const float* __restrict__ bias, unsigned short* __restrict__ Cout) {
  __shared__ unsigned short lds_a[128 * 64];
  __shared__ unsigned short lds_b[128 * 64];
  const int t = threadIdx.x;
  const int l = t & 63, w = t >> 6;
  const int wm = w >> 1, wn = w & 1;
  const int lr = l & 15, lq = l >> 4;
  const int2 bid = swz_bid();
  const size_t arow0 = (size_t)bid.y * 128;
  const size_t brow0 = (size_t)bid.x * 128;
  int pr[4], pco[4];
#pragma unroll
  for (int p = 0; p < 4; ++p) {
    int pc = p * 256 + t;
    pr[p] = pc >> 3;
    pco[p] = ((pc & 7) ^ (pr[p] & 7)) * 8;
  }

  f32x4 acc[4][4];
  for (int i = 0; i < 4; i++)
    for (int j = 0; j < 4; j++) acc[i][j] = (f32x4){0.f, 0.f, 0.f, 0.f};

  for (int kk = 0; kk < 16; ++kk) {
    const int k0 = kk * 64;
    __syncthreads();
#pragma unroll
    for (int p = 0; p < 4; ++p) {
      glds16(A + (arow0 + pr[p]) * HD + k0 + pco[p], lds_a + (p * 256 + t) * 8);
      glds16(W + (brow0 + pr[p]) * HD + k0 + pco[p], lds_b + (p * 256 + t) * 8);
    }
    __syncthreads();
#pragma unroll
    for (int h = 0; h < 2; ++h) {
      bf16x8 af[4], bfr[4];
      for (int mt = 0; mt < 4; ++mt)
        af[mt] = *(const bf16x8*)(lds_a + swz64(wm * 64 + mt * 16 + lr, h * 4 + lq));
      for (int nt = 0; nt < 4; ++nt)
        bfr[nt] = *(const bf16x8*)(lds_b + swz64(wn * 64 + nt * 16 + lr, h * 4 + lq));
      for (int mt = 0; mt < 4; ++mt)
        for (int nt = 0; nt < 4; ++nt)
          acc[mt][nt] = __builtin_amdgcn_mfma_f32_16x16x32_bf16(af[mt], bfr[nt], acc[mt][nt], 0, 0, 0);
    }
  }

  for (int nt = 0; nt < 4; ++nt) {
    int n = bid.x * 128 + wn * 64 + nt * 16 + lr;
    float bvv = bias[n];
    for (int mt = 0; mt < 4; ++mt) {
      size_t mbase = arow0 + wm * 64 + mt * 16 + lq * 4;
      for (int r = 0; r < 4; ++r)
        Cout[(mbase + r) * HD + n] = f2bf(acc[mt][nt][r] + bvv);
    }
  }
}

// ---------------- fused K+V GEMM: BK=32 double-buffer, counted vmcnt pipeline ----------------
__global__ __launch_bounds__(256, 2) void gemm_kv_kernel(
    const unsigned short* __restrict__ A, const unsigned short* __restrict__ Wk,
    const unsigned short* __restrict__ Wv, const float* __restrict__ bk,
    const float* __restrict__ bv, unsigned short* __restrict__ Kout,
    unsigned short* __restrict__ Vt) {
  __shared__ unsigned short lds_a[2][128 * 32];
  __shared__ unsigned short lds_k[2][128 * 32];
  __shared__ unsigned short lds_v[2][128 * 32];
  const int t = threadIdx.x;
  const int l = t & 63, w = t >> 6;
  const int wm = w >> 1, wn = w & 1;
  const int lr = l & 15, lq = l >> 4;
  const int2 bid = swz_bid();
  const size_t arow0 = (size_t)bid.y * 128;
  const size_t brow0 = (size_t)bid.x * 128;
  // staging inverse map: physical chunk pc -> logical (row, col-chunk)
  int pr[2], pco[2];
#pragma unroll
  for (int p = 0; p < 2; ++p) {
    int pc = p * 256 + t;
    int lr8 = pc >> 3;
    int e = (pc & 7) ^ (lr8 & 7);
    pr[p] = lr8 * 2 + (e >> 2);
    pco[p] = (e & 3) * 8;
  }

  f32x4 acck[4][4], accv[4][4];
  for (int i = 0; i < 4; i++)
    for (int j = 0; j < 4; j++) {
      acck[i][j] = (f32x4){0.f, 0.f, 0.f, 0.f};
      accv[i][j] = (f32x4){0.f, 0.f, 0.f, 0.f};
    }

  auto stage = [&](int buf, int k0) {  // 6 glds16, linear LDS dest, pre-swizzled source
#pragma unroll
    for (int p = 0; p < 2; ++p) {
      glds16(A + (arow0 + pr[p]) * HD + k0 + pco[p], lds_a[buf] + (p * 256 + t) * 8);
      glds16(Wk + (brow0 + pr[p]) * HD + k0 + pco[p], lds_k[buf] + (p * 256 + t) * 8);
      glds16(Wv + (brow0 + pr[p]) * HD + k0 + pco[p], lds_v[buf] + (p * 256 + t) * 8);
    }
  };
  auto compute = [&](int buf) {
    bf16x8 af[4];
    for (int mt = 0; mt < 4; ++mt)
      af[mt] = *(const bf16x8*)(lds_a[buf] + swz32(wm * 64 + mt * 16 + lr, lq));
    {
      bf16x8 bfr[4];
      for (int nt = 0; nt < 4; ++nt)
        bfr[nt] = *(const bf16x8*)(lds_k[buf] + swz32(wn * 64 + nt * 16 + lr, lq));
      for (int mt = 0; mt < 4; ++mt)
        for (int nt = 0; nt < 4; ++nt)
          acck[mt][nt] = __builtin_amdgcn_mfma_f32_16x16x32_bf16(af[mt], bfr[nt], acck[mt][nt], 0, 0, 0);
    }
    {
      bf16x8 bfr[4];
      for (int nt = 0; nt < 4; ++nt)
        bfr[nt] = *(const bf16x8*)(lds_v[buf] + swz32(wn * 64 + nt * 16 + lr, lq));
      for (int mt = 0; mt < 4; ++mt)
        for (int nt = 0; nt < 4; ++nt)
          accv[mt][nt] = __builtin_amdgcn_mfma_f32_16x16x32_bf16(af[mt], bfr[nt], accv[mt][nt], 0, 0, 0);
    }
  };

  // pipeline: stage(next) in flight across compute(cur); counted vmcnt, never 0 in loop
  stage(0, 0);
  for (int kk = 0; kk < 31; ++kk) {
    const int cur = kk & 1;
    stage(cur ^ 1, (kk + 1) * 32);                  // 6 newer loads in flight
    asm volatile("s_waitcnt vmcnt(6)" ::: "memory");  // drain only buf[cur]'s 6
    __builtin_amdgcn_s_barrier();                   // all waves: buf[cur] ready
    compute(cur);
    __builtin_amdgcn_s_barrier();                   // all reads of buf[cur] done
  }
  asm volatile("s_waitcnt vmcnt(0)" ::: "memory");
  __builtin_amdgcn_s_barrier();
  compute(1);

  // K store (row-major bf16)
  for (int nt = 0; nt < 4; ++nt) {
    int n = bid.x * 128 + wn * 64 + nt * 16 + lr;
    float bvv = bk[n];
    for (int mt = 0; mt < 4; ++mt) {
      size_t mbase = arow0 + wm * 64 + mt * 16 + lq * 4;
      for (int r = 0; r < 4; ++r)
        Kout[(mbase + r) * HD + n] = f2bf(acck[mt][nt][r] + bvv);
    }
  }
  // V store (transposed per (bc,head) layout for the attention PV step)
  for (int nt = 0; nt < 4; ++nt) {
    int n = bid.x * 128 + wn * 64 + nt * 16 + lr;
    float bvv = bv[n];
    int h = n >> 6, d = n & 63;
    for (int mt = 0; mt < 4; ++mt) {
      size_t m0 = arow0 + wm * 64 + mt * 16 + lq * 4;
      size_t bc = m0 >> 8, j = m0 & 255;
      *(ushort4*)(Vt + ((bc * 16 + h) * 64 + d) * 256 + j) =
          make_ushort4(f2bf(accv[mt][nt][0] + bvv), f2bf(accv[mt][nt][1] + bvv),
                       f2bf(accv[mt][nt][2] + bvv), f2bf(accv[mt][nt][3] + bvv));
    }
  }
}

// ---------------- fallback GEMM (fp32 in, register cvt staging) ----------------
__global__ __launch_bounds__(256, 2) void gemm_f32_kernel(
    const float* __restrict__ A, const float* __restrict__ W,
    const float* __restrict__ bias, unsigned short* __restrict__ Cout,
    int store_vt, int qremap) {
  __shared__ unsigned short lds_a[128 * 32];
  __shared__ unsigned short lds_b[128 * 32];
  const int t = threadIdx.x;
  const int l = t & 63, w = t >> 6;
  const int wm = w >> 1, wn = w & 1;
  const int lr = l & 15, lq = l >> 4;
  const size_t arow0 = (size_t)blockIdx.y * 128;
  const size_t brow0 = (size_t)blockIdx.x * 128;

  f32x4 acc[4][4];
  for (int i = 0; i < 4; i++)
    for (int j = 0; j < 4; j++) acc[i][j] = (f32x4){0.f, 0.f, 0.f, 0.f};

  for (int kk = 0; kk < 32; ++kk) {
    const int k0 = kk * 32;
    uint4 av[2], bv[2];
    for (int p = 0; p < 2; ++p) {
      int chunk = p * 256 + t;
      int row = chunk >> 2, c8 = (chunk & 3) * 8;
      size_t grow = arow0 + row;
      bool valid = true;
      const float* srcA;
      if (qremap) {
        int bb = (int)(grow >> 11), tt = (int)(grow & 2047);
        valid = tt < 1985;
        srcA = A + ((size_t)(bb << 11) + tt + 63) * HD + k0 + c8;
      } else {
        srcA = A + grow * HD + k0 + c8;
      }
      if (valid) {
        float4 x = *(const float4*)srcA, y = *(const float4*)(srcA + 4);
        av[p] = make_uint4(pk2bf(x.x, x.y), pk2bf(x.z, x.w), pk2bf(y.x, y.y), pk2bf(y.z, y.w));
      } else av[p] = make_uint4(0, 0, 0, 0);
      const float* srcB = W + (brow0 + row) * HD + k0 + c8;
      float4 x = *(const float4*)srcB, y = *(const float4*)(srcB + 4);
      bv[p] = make_uint4(pk2bf(x.x, x.y), pk2bf(x.z, x.w), pk2bf(y.y, y.y), pk2bf(y.z, y.w));
    }
    // fix accidental typo-proofing: recompute bv[p] correctly
    for (int p = 0; p < 2; ++p) {
      int chunk = p * 256 + t;
      int row = chunk >> 2, c8 = (chunk & 3) * 8;
      const float* srcB = W + (brow0 + row) * HD + k0 + c8;
      float4 x = *(const float4*)srcB, y = *(const float4*)(srcB + 4);
      bv[p] = make_uint4(pk2bf(x.x, x.y), pk2bf(x.z, x.w), pk2bf(y.x, y.y), pk2bf(y.z, y.w));
    }
    __syncthreads();
    for (int p = 0; p < 2; ++p) {
      int chunk = p * 256 + t;
      *(uint4*)(lds_a + chunk * 8) = av[p];
      *(uint4*)(lds_b + chunk * 8) = bv[p];
    }
    __syncthreads();
    bf16x8 af[4], bfr[4];
    for (int mt = 0; mt < 4; ++mt)
      af[mt] = *(const bf16x8*)(lds_a + (wm * 64 + mt * 16 + lr) * 32 + lq * 8);
    for (int nt = 0; nt < 4; ++nt)
      bfr[nt] = *(const bf16x8*)(lds_b + (wn * 64 + nt * 16 + lr) * 32 + lq * 8);
    for (int mt = 0; mt < 4; ++mt)
      for (int nt = 0; nt < 4; ++nt)
        acc[mt][nt] = __builtin_amdgcn_mfma_f32_16x16x32_bf16(af[mt], bfr[nt], acc[mt][nt], 0, 0, 0);
  }

  if (!store_vt) {
    for (int nt = 0; nt < 4; ++nt) {
      int n = blockIdx.x * 128 + wn * 64 + nt * 16 + lr;
      float bvv = bias[n];
      for (int mt = 0; mt < 4; ++mt) {
        size_t mbase = arow0 + wm * 64 + mt * 16 + lq * 4;
        for (int r = 0; r < 4; ++r)
          Cout[(mbase + r) * HD + n] = f2bf(acc[mt][nt][r] + bvv);
      }
    }
  } else {
    for (int nt = 0; nt < 4; ++nt) {
      int n = blockIdx.x * 128 + wn * 64 + nt * 16 + lr;
      float bvv = bias[n];
      int h = n >> 6, d = n & 63;
      for (int mt = 0; mt < 4; ++mt) {
        size_t m0 = arow0 + wm * 64 + mt * 16 + lq * 4;
        size_t bc = m0 >> 8, j = m0 & 255;
        *(ushort4*)(Cout + ((bc * 16 + h) * 64 + d) * 256 + j) =
            make_ushort4(f2bf(acc[mt][nt][0] + bvv), f2bf(acc[mt][nt][1] + bvv),
                         f2bf(acc[mt][nt][2] + bvv), f2bf(acc[mt][nt][3] + bvv));
      }
    }
  }
}

// ---------------- fused attention per (b, c, head); swapped QK^T, V direct from Vt ----------------
#define QK_STRIDE 72
#define P_STRIDE 260

__global__ __launch_bounds__(256, 3) void attn_kernel(
    const unsigned short* __restrict__ Qp, const unsigned short* __restrict__ Kp,
    const unsigned short* __restrict__ Vt, float* __restrict__ out) {
  __shared__ unsigned short k_s[256 * QK_STRIDE];   // 36864 B; P overlay 64x260 (33280 B) fits
  const int t = threadIdx.x;
  const int l = t & 63, w = t >> 6;
  const int lr = l & 15, lq = l >> 4;
  const int bid = blockIdx.x;
  const int head = bid & 15, cc = (bid >> 4) & 31, b = bid >> 9;
  const size_t qrow0 = (size_t)(b * NC + cc) * 64;
  const size_t kvrow0 = (size_t)(b * NC + cc) * 256;
  const int hcol = head * 64;
  const unsigned short* vbase = Vt + ((size_t)((b * NC + cc) * 16 + head) * 64) * 256;

  for (int p = 0; p < 8; ++p) {
    int chunk = p * 256 + t;
    int row = chunk >> 3, c8 = (chunk & 7) * 8;
    *(uint4*)(k_s + row * QK_STRIDE + c8) = *(const uint4*)(Kp + (kvrow0 + row) * HD + hcol + c8);
  }
  // Q straight to registers (B-operand rows w*16+lr)
  bf16x8 qa0 = ld_frag8(Qp + (qrow0 + w * 16 + lr) * HD + hcol + lq * 8);
  bf16x8 qa1 = ld_frag8(Qp + (qrow0 + w * 16 + lr) * HD + hcol + 32 + lq * 8);
  __syncthreads();

  // swapped QK^T: A=K rows, B=Q rows -> lane holds P[k = nt*16+lq*4+r][q = w*16+lr]
  f32x4 sc[16];
  __builtin_amdgcn_s_setprio(1);
  for (int nt = 0; nt < 16; ++nt) {
    bf16x8 kb0 = ld_frag8(k_s + (nt * 16 + lr) * QK_STRIDE + lq * 8);
    bf16x8 kb1 = ld_frag8(k_s + (nt * 16 + lr) * QK_STRIDE + 32 + lq * 8);
    f32x4 a = (f32x4){0.f, 0.f, 0.f, 0.f};
    a = __builtin_amdgcn_mfma_f32_16x16x32_bf16(kb0, qa0, a, 0, 0, 0);
    a = __builtin_amdgcn_mfma_f32_16x16x32_bf16(kb1, qa1, a, 0, 0, 0);
    sc[nt] = a;
  }
  __builtin_amdgcn_s_setprio(0);

  // row stats are lane-local now: reduce in-lane, then across the 4 lanes sharing lr
  float m = -1e30f;
  for (int nt = 0; nt < 16; ++nt)
    for (int r = 0; r < 4; ++r) m = fmaxf(m, sc[nt][r]);
  m = fmaxf(m, __shfl_xor(m, 16));
  m = fmaxf(m, __shfl_xor(m, 32));
  float s = 0.f;
  const float cexp = 0.18033688011112042f;  // log2(e)/8
  for (int nt = 0; nt < 16; ++nt)
    for (int r = 0; r < 4; ++r) {
      float p = exp2f((sc[nt][r] - m) * cexp);
      sc[nt][r] = p;
      s += p;
    }
  s += __shfl_xor(s, 16);
  s += __shfl_xor(s, 32);

  // T14: issue V(ks=0) loads now; HBM latency hides under barrier + P-writes
  bf16x8 va[4];
#pragma unroll
  for (int nt2 = 0; nt2 < 4; ++nt2)
    va[nt2] = *(const bf16x8*)(vbase + (size_t)(nt2 * 16 + lr) * 256 + lq * 8);

  __syncthreads();  // all waves done reading k_s -> reuse as P

  // packed P-writes: lane holds 4 CONSECUTIVE k per nt -> one 8B write each
  for (int nt = 0; nt < 16; ++nt) {
    *(uint2*)(k_s + (w * 16 + lr) * P_STRIDE + nt * 16 + lq * 4) =
        make_uint2(pk2bf(sc[nt][0], sc[nt][1]), pk2bf(sc[nt][2], sc[nt][3]));
  }
  // each wave reads only its own P rows (written above); compiler orders ds_write->ds_read

  f32x4 o[4];
  for (int i = 0; i < 4; ++i) o[i] = (f32x4){0.f, 0.f, 0.f, 0.f};
  bf16x8 vbuf[4];
#pragma unroll
  for (int ks = 0; ks < 8; ks += 2) {
#pragma unroll
    for (int nt2 = 0; nt2 < 4; ++nt2)
      vbuf[nt2] = *(const bf16x8*)(vbase + (size_t)(nt2 * 16 + lr) * 256 + (ks + 1) * 32 + lq * 8);
    bf16x8 pa = ld_frag8(k_s + (w * 16 + lr) * P_STRIDE + ks * 32 + lq * 8);
    __builtin_amdgcn_s_setprio(1);
#pragma unroll
    for (int nt2 = 0; nt2 < 4; ++nt2)
      o[nt2] = __builtin_amdgcn_mfma_f32_16x16x32_bf16(pa, va[nt2], o[nt2], 0, 0, 0);
    __builtin_amdgcn_s_setprio(0);
    if (ks + 2 < 8) {
#pragma unroll
      for (int nt2 = 0; nt2 < 4; ++nt2)
        va[nt2] = *(const bf16x8*)(vbase + (size_t)(nt2 * 16 + lr) * 256 + (ks + 2) * 32 + lq * 8);
    }
    bf16x8 pb = ld_frag8(k_s + (w * 16 + lr) * P_STRIDE + (ks + 1) * 32 + lq * 8);
    __builtin_amdgcn_s_setprio(1);
#pragma unroll
    for (int nt2 = 0; nt2 < 4; ++nt2)
      o[nt2] = __builtin_amdgcn_mfma_f32_16x16x32_bf16(pb, vbuf[nt2], o[nt2], 0, 0, 0);
    __builtin_amdgcn_s_setprio(0);
  }

  for (int r = 0; r < 4; ++r) {
    int strip = w * 16 + lq * 4 + r;
    int trow = cc * 64 + strip;
    float sv = __shfl(s, lq * 4 + r, 16);  // row-sum for q = w*16+lq*4+r
    if (trow < 1985) {
      size_t orow = (size_t)b * SEQ + trow + 63;
      float inv = 1.0f / sv;
      for (int nt2 = 0; nt2 < 4; ++nt2)
        out[orow * HD + hcol + nt2 * 16 + lr] = o[nt2][r] * inv;
    }
  }
}

extern "C" void kernel_launch(void* const* d_in, const int* in_sizes, int n_in,
                              void* d_out, int out_size, void* d_ws, size_t ws_size,
                              hipStream_t stream) {
  (void)in_sizes; (void)n_in; (void)out_size;
  const float* query = (const float*)d_in[0];
  const float* kv    = (const float*)d_in[1];
  const float* Wq    = (const float*)d_in[2];
  const float* bq    = (const float*)d_in[3];
  const float* Wk    = (const float*)d_in[4];
  const float* bk    = (const float*)d_in[5];
  const float* Wv    = (const float*)d_in[6];
  const float* bv    = (const float*)d_in[7];
  float* out = (float*)d_out;

  unsigned short* Qp  = (unsigned short*)d_ws;          // 8192x1024
  unsigned short* Kp  = Qp + (size_t)8192 * 1024;       // 32768x1024
  unsigned short* Vt  = Kp + (size_t)32768 * 1024;      // 32768x1024 (transposed layout)
  unsigned short* Qbf = Vt + (size_t)32768 * 1024;      // 8192x1024
  unsigned short* KVb = Qbf + (size_t)8192 * 1024;      // 32768x1024
  unsigned short* Wqb = KVb + (size_t)32768 * 1024;     // 1024x1024 x3 (contiguous)
  const size_t need = ((size_t)8192 * 1024 * 2 + (size_t)32768 * 1024 * 2 + (size_t)1024 * 1024 * 3) * 2;
  const bool big = ws_size >= need;

  if (big) {
    prep_q_kernel<<<dim3(4348), dim3(256), 0, stream>>>(query, Qbf, out);
    cvt_w3_kernel<<<dim3(1536), dim3(256), 0, stream>>>(Wq, Wk, Wv, Wqb);
    cvt_kernel<<<dim3(16384), dim3(256), 0, stream>>>(kv, KVb, 4194304);
    gemm_q_kernel<<<dim3(8, 64), dim3(256), 0, stream>>>(Qbf, Wqb, bq, Qp);
    gemm_kv_kernel<<<dim3(8, 256), dim3(256), 0, stream>>>(KVb, Wqb + (size_t)1048576,
                                                           Wqb + (size_t)2097152, bk, bv, Kp, Vt);
  } else {
    zero_head_kernel<<<dim3(252), dim3(256), 0, stream>>>(out);
    gemm_f32_kernel<<<dim3(8, 64), dim3(256), 0, stream>>>(query, Wq, bq, Qp, 0, 1);
    gemm_f32_kernel<<<dim3(8, 256), dim3(256), 0, stream>>>(kv, Wk, bk, Kp, 0, 0);
    gemm_f32_kernel<<<dim3(8, 256), dim3(256), 0, stream>>>(kv, Wv, bv, Vt, 1, 0);
  }
  attn_kernel<<<dim3(2048), dim3(256), 0, stream>>>(Qp, Kp, Vt, out);
}

// Round 5
// 461.485 us; speedup vs baseline: 1.0118x; 1.0118x over previous
//
#include <hip/hip_runtime.h>
#include <stdint.h>

#define HD 1024
#define SEQ 2048
#define NC 32

typedef __bf16 bf16x4 __attribute__((ext_vector_type(4)));
typedef __bf16 bf16x8 __attribute__((ext_vector_type(8)));
typedef float f32x4 __attribute__((ext_vector_type(4)));

__device__ inline unsigned short f2bf(float f) {
  union { float f; unsigned int u; } v; v.f = f;
  unsigned int r = v.u + 0x7fffu + ((v.u >> 16) & 1u);
  return (unsigned short)(r >> 16);
}
__device__ inline unsigned int pk2bf(float a, float b) {
  return (unsigned int)f2bf(a) | ((unsigned int)f2bf(b) << 16);
}
__device__ inline bf16x8 ld_frag8(const unsigned short* p) {
  bf16x4 lo = *(const bf16x4*)p;
  bf16x4 hi = *(const bf16x4*)(p + 4);
  return __builtin_shufflevector(lo, hi, 0, 1, 2, 3, 4, 5, 6, 7);
}
// async 16B global->LDS (wave-uniform base + lane*16; LDS dest stays LINEAR)
__device__ inline void glds16(const unsigned short* g, unsigned short* l) {
  __builtin_amdgcn_global_load_lds(
      (const __attribute__((address_space(1))) unsigned int*)g,
      (__attribute__((address_space(3))) unsigned int*)l, 16, 0, 0);
}
// ---- 128x64 bf16 tile swizzle: 8 col-chunks (16B) per row; involutive per-row XOR.
// Measured R3: SQ_LDS_BANK_CONFLICT == 0 with this layout.
__device__ inline int swz64(int row, int j) { return (row * 8 + (j ^ (row & 7))) * 8; }

// ---------------- zero rows s<63 of output (fallback path only) ----------------
__global__ __launch_bounds__(256) void zero_head_kernel(float* __restrict__ out) {
  int i = (blockIdx.x * 256 + threadIdx.x) * 4;
  int b = i / 64512;
  int r = i - b * 64512;
  *(float4*)(out + (size_t)b * (SEQ * HD) + r) = make_float4(0.f, 0.f, 0.f, 0.f);
}

// ---------------- ALL prep work in ONE dispatch ----------------
// blocks [0,16384): kv fp32->bf16   (33.5M elems)
// blocks [16384,20480): query remap+pad -> bf16 (8192x1024)
// blocks [20480,22016): Wq|Wk|Wv fp32->bf16 (3x 1M)
// blocks [22016,22268): zero out[b, 0:63, :]
__global__ __launch_bounds__(256) void prep_all_kernel(
    const float* __restrict__ query, const float* __restrict__ kv,
    const float* __restrict__ Wq, const float* __restrict__ Wk,
    const float* __restrict__ Wv, unsigned short* __restrict__ Qbf,
    unsigned short* __restrict__ KVb, unsigned short* __restrict__ Wb,
    float* __restrict__ oz) {
  int bid = blockIdx.x;
  if (bid < 16384) {  // kv convert: 8 elems/thread
    int i = bid * 256 + threadIdx.x;
    float4 a = ((const float4*)kv)[(size_t)i * 2];
    float4 b = ((const float4*)kv)[(size_t)i * 2 + 1];
    ((uint4*)KVb)[i] = make_uint4(pk2bf(a.x, a.y), pk2bf(a.z, a.w),
                                  pk2bf(b.x, b.y), pk2bf(b.z, b.w));
    return;
  }
  bid -= 16384;
  if (bid < 4096) {  // query remap+pad
    int i = bid * 256 + threadIdx.x;  // [0, 8192*128)
    int g = i >> 7, c8 = (i & 127) * 8;
    int b = g >> 11, tt = g & 2047;
    uint4 o = make_uint4(0, 0, 0, 0);
    if (tt < 1985) {
      const float* src = query + ((size_t)(b << 11) + tt + 63) * HD + c8;
      float4 a = *(const float4*)src;
      float4 bb = *(const float4*)(src + 4);
      o = make_uint4(pk2bf(a.x, a.y), pk2bf(a.z, a.w), pk2bf(bb.x, bb.y), pk2bf(bb.z, bb.w));
    }
    *(uint4*)(Qbf + (size_t)g * HD + c8) = o;
    return;
  }
  bid -= 4096;
  if (bid < 1536) {  // weights: 512 blocks per matrix
    int which = bid >> 9;
    int i = (bid & 511) * 256 + threadIdx.x;
    const float* src = which == 0 ? Wq : (which == 1 ? Wk : Wv);
    float4 a = ((const float4*)src)[(size_t)i * 2];
    float4 b = ((const float4*)src)[(size_t)i * 2 + 1];
    ((uint4*)(Wb + (size_t)which * 1048576))[i] =
        make_uint4(pk2bf(a.x, a.y), pk2bf(a.z, a.w), pk2bf(b.x, b.y), pk2bf(b.z, b.w));
    return;
  }
  bid -= 1536;  // zero head rows
  int i = (bid * 256 + threadIdx.x) * 4;
  int b = i / 64512;
  int r = i - b * 64512;
  *(float4*)(oz + (size_t)b * (SEQ * HD) + r) = make_float4(0.f, 0.f, 0.f, 0.f);
}

// ---------------- merged GEMM dispatch: y<256 => fused K+V tiles, y>=256 => Q tiles ----------------
// Both paths are the R3-measured structure (BK=64, 2 barriers/step, swz64, glds16).
__global__ __launch_bounds__(256, 2) void gemm_all_kernel(
    const unsigned short* __restrict__ Qbf, const unsigned short* __restrict__ KVb,
    const unsigned short* __restrict__ Wb,  // Wq | Wk | Wv contiguous (1M each)
    const float* __restrict__ bq, const float* __restrict__ bk, const float* __restrict__ bv,
    unsigned short* __restrict__ Qp, unsigned short* __restrict__ Kp,
    unsigned short* __restrict__ Vt) {
  __shared__ unsigned short lds_a[128 * 64];
  __shared__ unsigned short lds_b[128 * 64];
  __shared__ unsigned short lds_c[128 * 64];
  const int t = threadIdx.x;
  const int l = t & 63, w = t >> 6;
  const int wm = w >> 1, wn = w & 1;
  const int lr = l & 15, lq = l >> 4;
  // staging inverse map: physical chunk pc -> (row, pre-swizzled col-chunk)
  int pr[4], pco[4];
#pragma unroll
  for (int p = 0; p < 4; ++p) {
    int pc = p * 256 + t;
    pr[p] = pc >> 3;
    pco[p] = ((pc & 7) ^ (pr[p] & 7)) * 8;
  }

  if (blockIdx.y < 256) {
    // ================= fused K+V GEMM (M=32768) =================
    int lin = blockIdx.y * 8 + blockIdx.x;            // [0,2048)
    int s = (lin & 7) * 256 + (lin >> 3);             // bijective XCD swizzle
    const int bx = s & 7, by = s >> 3;
    const size_t arow0 = (size_t)by * 128;
    const size_t brow0 = (size_t)bx * 128;
    const unsigned short* Wk = Wb + (size_t)1048576;
    const unsigned short* Wv = Wb + (size_t)2097152;

    f32x4 acck[4][4], accv[4][4];
    for (int i = 0; i < 4; i++)
      for (int j = 0; j < 4; j++) {
        acck[i][j] = (f32x4){0.f, 0.f, 0.f, 0.f};
        accv[i][j] = (f32x4){0.f, 0.f, 0.f, 0.f};
      }

    for (int kk = 0; kk < 16; ++kk) {
      const int k0 = kk * 64;
      __syncthreads();
#pragma unroll
      for (int p = 0; p < 4; ++p) {
        glds16(KVb + (arow0 + pr[p]) * HD + k0 + pco[p], lds_a + (p * 256 + t) * 8);
        glds16(Wk + (brow0 + pr[p]) * HD + k0 + pco[p], lds_b + (p * 256 + t) * 8);
        glds16(Wv + (brow0 + pr[p]) * HD + k0 + pco[p], lds_c + (p * 256 + t) * 8);
      }
      __syncthreads();
#pragma unroll
      for (int h = 0; h < 2; ++h) {
        bf16x8 af[4];
        for (int mt = 0; mt < 4; ++mt)
          af[mt] = *(const bf16x8*)(lds_a + swz64(wm * 64 + mt * 16 + lr, h * 4 + lq));
        {
          bf16x8 bfr[4];
          for (int nt = 0; nt < 4; ++nt)
            bfr[nt] = *(const bf16x8*)(lds_b + swz64(wn * 64 + nt * 16 + lr, h * 4 + lq));
          for (int mt = 0; mt < 4; ++mt)
            for (int nt = 0; nt < 4; ++nt)
              acck[mt][nt] = __builtin_amdgcn_mfma_f32_16x16x32_bf16(af[mt], bfr[nt], acck[mt][nt], 0, 0, 0);
        }
        {
          bf16x8 bfr[4];
          for (int nt = 0; nt < 4; ++nt)
            bfr[nt] = *(const bf16x8*)(lds_c + swz64(wn * 64 + nt * 16 + lr, h * 4 + lq));
          for (int mt = 0; mt < 4; ++mt)
            for (int nt = 0; nt < 4; ++nt)
              accv[mt][nt] = __builtin_amdgcn_mfma_f32_16x16x32_bf16(af[mt], bfr[nt], accv[mt][nt], 0, 0, 0);
        }
      }
    }

    // K store (row-major bf16)
    for (int nt = 0; nt < 4; ++nt) {
      int n = bx * 128 + wn * 64 + nt * 16 + lr;
      float bvv = bk[n];
      for (int mt = 0; mt < 4; ++mt) {
        size_t mbase = arow0 + wm * 64 + mt * 16 + lq * 4;
        for (int r = 0; r < 4; ++r)
          Kp[(mbase + r) * HD + n] = f2bf(acck[mt][nt][r] + bvv);
      }
    }
    // V store (transposed per (bc,head) layout for attention PV)
    for (int nt = 0; nt < 4; ++nt) {
      int n = bx * 128 + wn * 64 + nt * 16 + lr;
      float bvv = bv[n];
      int h = n >> 6, d = n & 63;
      for (int mt = 0; mt < 4; ++mt) {
        size_t m0 = arow0 + wm * 64 + mt * 16 + lq * 4;
        size_t bc = m0 >> 8, j = m0 & 255;
        *(ushort4*)(Vt + ((bc * 16 + h) * 64 + d) * 256 + j) =
            make_ushort4(f2bf(accv[mt][nt][0] + bvv), f2bf(accv[mt][nt][1] + bvv),
                         f2bf(accv[mt][nt][2] + bvv), f2bf(accv[mt][nt][3] + bvv));
      }
    }
  } else {
    // ================= Q GEMM (M=8192) =================
    int lin = (blockIdx.y - 256) * 8 + blockIdx.x;    // [0,512)
    int s = (lin & 7) * 64 + (lin >> 3);              // bijective XCD swizzle
    const int bx = s & 7, by = s >> 3;
    const size_t arow0 = (size_t)by * 128;
    const size_t brow0 = (size_t)bx * 128;

    f32x4 acc[4][4];
    for (int i = 0; i < 4; i++)
      for (int j = 0; j < 4; j++) acc[i][j] = (f32x4){0.f, 0.f, 0.f, 0.f};

    for (int kk = 0; kk < 16; ++kk) {
      const int k0 = kk * 64;
      __syncthreads();
#pragma unroll
      for (int p = 0; p < 4; ++p) {
        glds16(Qbf + (arow0 + pr[p]) * HD + k0 + pco[p], lds_a + (p * 256 + t) * 8);
        glds16(Wb + (brow0 + pr[p]) * HD + k0 + pco[p], lds_b + (p * 256 + t) * 8);
      }
      __syncthreads();
#pragma unroll
      for (int h = 0; h < 2; ++h) {
        bf16x8 af[4], bfr[4];
        for (int mt = 0; mt < 4; ++mt)
          af[mt] = *(const bf16x8*)(lds_a + swz64(wm * 64 + mt * 16 + lr, h * 4 + lq));
        for (int nt = 0; nt < 4; ++nt)
          bfr[nt] = *(const bf16x8*)(lds_b + swz64(wn * 64 + nt * 16 + lr, h * 4 + lq));
        for (int mt = 0; mt < 4; ++mt)
          for (int nt = 0; nt < 4; ++nt)
            acc[mt][nt] = __builtin_amdgcn_mfma_f32_16x16x32_bf16(af[mt], bfr[nt], acc[mt][nt], 0, 0, 0);
      }
    }

    for (int nt = 0; nt < 4; ++nt) {
      int n = bx * 128 + wn * 64 + nt * 16 + lr;
      float bvv = bq[n];
      for (int mt = 0; mt < 4; ++mt) {
        size_t mbase = arow0 + wm * 64 + mt * 16 + lq * 4;
        for (int r = 0; r < 4; ++r)
          Qp[(mbase + r) * HD + n] = f2bf(acc[mt][nt][r] + bvv);
      }
    }
  }
}

// ---------------- fallback GEMM (fp32 in, register cvt staging) ----------------
__global__ __launch_bounds__(256, 2) void gemm_f32_kernel(
    const float* __restrict__ A, const float* __restrict__ W,
    const float* __restrict__ bias, unsigned short* __restrict__ Cout,
    int store_vt, int qremap) {
  __shared__ unsigned short lds_a[128 * 32];
  __shared__ unsigned short lds_b[128 * 32];
  const int t = threadIdx.x;
  const int l = t & 63, w = t >> 6;
  const int wm = w >> 1, wn = w & 1;
  const int lr = l & 15, lq = l >> 4;
  const size_t arow0 = (size_t)blockIdx.y * 128;
  const size_t brow0 = (size_t)blockIdx.x * 128;

  f32x4 acc[4][4];
  for (int i = 0; i < 4; i++)
    for (int j = 0; j < 4; j++) acc[i][j] = (f32x4){0.f, 0.f, 0.f, 0.f};

  for (int kk = 0; kk < 32; ++kk) {
    const int k0 = kk * 32;
    uint4 av[2], bv[2];
    for (int p = 0; p < 2; ++p) {
      int chunk = p * 256 + t;
      int row = chunk >> 2, c8 = (chunk & 3) * 8;
      size_t grow = arow0 + row;
      bool valid = true;
      const float* srcA;
      if (qremap) {
        int bb = (int)(grow >> 11), tt = (int)(grow & 2047);
        valid = tt < 1985;
        srcA = A + ((size_t)(bb << 11) + tt + 63) * HD + k0 + c8;
      } else {
        srcA = A + grow * HD + k0 + c8;
      }
      if (valid) {
        float4 x = *(const float4*)srcA, y = *(const float4*)(srcA + 4);
        av[p] = make_uint4(pk2bf(x.x, x.y), pk2bf(x.z, x.w), pk2bf(y.x, y.y), pk2bf(y.z, y.w));
      } else av[p] = make_uint4(0, 0, 0, 0);
      const float* srcB = W + (brow0 + row) * HD + k0 + c8;
      float4 x = *(const float4*)srcB, y = *(const float4*)(srcB + 4);
      bv[p] = make_uint4(pk2bf(x.x, x.y), pk2bf(x.z, x.w), pk2bf(y.x, y.y), pk2bf(y.z, y.w));
    }
    __syncthreads();
    for (int p = 0; p < 2; ++p) {
      int chunk = p * 256 + t;
      *(uint4*)(lds_a + chunk * 8) = av[p];
      *(uint4*)(lds_b + chunk * 8) = bv[p];
    }
    __syncthreads();
    bf16x8 af[4], bfr[4];
    for (int mt = 0; mt < 4; ++mt)
      af[mt] = *(const bf16x8*)(lds_a + (wm * 64 + mt * 16 + lr) * 32 + lq * 8);
    for (int nt = 0; nt < 4; ++nt)
      bfr[nt] = *(const bf16x8*)(lds_b + (wn * 64 + nt * 16 + lr) * 32 + lq * 8);
    for (int mt = 0; mt < 4; ++mt)
      for (int nt = 0; nt < 4; ++nt)
        acc[mt][nt] = __builtin_amdgcn_mfma_f32_16x16x32_bf16(af[mt], bfr[nt], acc[mt][nt], 0, 0, 0);
  }

  if (!store_vt) {
    for (int nt = 0; nt < 4; ++nt) {
      int n = blockIdx.x * 128 + wn * 64 + nt * 16 + lr;
      float bvv = bias[n];
      for (int mt = 0; mt < 4; ++mt) {
        size_t mbase = arow0 + wm * 64 + mt * 16 + lq * 4;
        for (int r = 0; r < 4; ++r)
          Cout[(mbase + r) * HD + n] = f2bf(acc[mt][nt][r] + bvv);
      }
    }
  } else {
    for (int nt = 0; nt < 4; ++nt) {
      int n = blockIdx.x * 128 + wn * 64 + nt * 16 + lr;
      float bvv = bias[n];
      int h = n >> 6, d = n & 63;
      for (int mt = 0; mt < 4; ++mt) {
        size_t m0 = arow0 + wm * 64 + mt * 16 + lq * 4;
        size_t bc = m0 >> 8, j = m0 & 255;
        *(ushort4*)(Cout + ((bc * 16 + h) * 64 + d) * 256 + j) =
            make_ushort4(f2bf(acc[mt][nt][0] + bvv), f2bf(acc[mt][nt][1] + bvv),
                         f2bf(acc[mt][nt][2] + bvv), f2bf(acc[mt][nt][3] + bvv));
      }
    }
  }
}

// ---------------- fused attention per (b, c, head); swapped QK^T, V direct from Vt ----------------
#define QK_STRIDE 72
#define P_STRIDE 260

__global__ __launch_bounds__(256, 3) void attn_kernel(
    const unsigned short* __restrict__ Qp, const unsigned short* __restrict__ Kp,
    const unsigned short* __restrict__ Vt, float* __restrict__ out) {
  __shared__ unsigned short k_s[256 * QK_STRIDE];   // 36864 B; P overlay 64x260 (33280 B) fits
  const int t = threadIdx.x;
  const int l = t & 63, w = t >> 6;
  const int lr = l & 15, lq = l >> 4;
  const int bid = blockIdx.x;
  const int head = bid & 15, cc = (bid >> 4) & 31, b = bid >> 9;
  const size_t qrow0 = (size_t)(b * NC + cc) * 64;
  const size_t kvrow0 = (size_t)(b * NC + cc) * 256;
  const int hcol = head * 64;
  const unsigned short* vbase = Vt + ((size_t)((b * NC + cc) * 16 + head) * 64) * 256;

  for (int p = 0; p < 8; ++p) {
    int chunk = p * 256 + t;
    int row = chunk >> 3, c8 = (chunk & 7) * 8;
    *(uint4*)(k_s + row * QK_STRIDE + c8) = *(const uint4*)(Kp + (kvrow0 + row) * HD + hcol + c8);
  }
  // Q straight to registers (B-operand rows w*16+lr)
  bf16x8 qa0 = ld_frag8(Qp + (qrow0 + w * 16 + lr) * HD + hcol + lq * 8);
  bf16x8 qa1 = ld_frag8(Qp + (qrow0 + w * 16 + lr) * HD + hcol + 32 + lq * 8);
  __syncthreads();

  // swapped QK^T: A=K rows, B=Q rows -> lane holds P[k = nt*16+lq*4+r][q = w*16+lr]
  f32x4 sc[16];
  __builtin_amdgcn_s_setprio(1);
  for (int nt = 0; nt < 16; ++nt) {
    bf16x8 kb0 = ld_frag8(k_s + (nt * 16 + lr) * QK_STRIDE + lq * 8);
    bf16x8 kb1 = ld_frag8(k_s + (nt * 16 + lr) * QK_STRIDE + 32 + lq * 8);
    f32x4 a = (f32x4){0.f, 0.f, 0.f, 0.f};
    a = __builtin_amdgcn_mfma_f32_16x16x32_bf16(kb0, qa0, a, 0, 0, 0);
    a = __builtin_amdgcn_mfma_f32_16x16x32_bf16(kb1, qa1, a, 0, 0, 0);
    sc[nt] = a;
  }
  __builtin_amdgcn_s_setprio(0);

  // row stats are lane-local now: reduce in-lane, then across the 4 lanes sharing lr
  float m = -1e30f;
  for (int nt = 0; nt < 16; ++nt)
    for (int r = 0; r < 4; ++r) m = fmaxf(m, sc[nt][r]);
  m = fmaxf(m, __shfl_xor(m, 16));
  m = fmaxf(m, __shfl_xor(m, 32));
  float s = 0.f;
  const float cexp = 0.18033688011112042f;  // log2(e)/8
  for (int nt = 0; nt < 16; ++nt)
    for (int r = 0; r < 4; ++r) {
      float p = exp2f((sc[nt][r] - m) * cexp);
      sc[nt][r] = p;
      s += p;
    }
  s += __shfl_xor(s, 16);
  s += __shfl_xor(s, 32);

  // T14: issue V(ks=0) loads now; HBM latency hides under barrier + P-writes
  bf16x8 va[4];
#pragma unroll
  for (int nt2 = 0; nt2 < 4; ++nt2)
    va[nt2] = *(const bf16x8*)(vbase + (size_t)(nt2 * 16 + lr) * 256 + lq * 8);

  __syncthreads();  // all waves done reading k_s -> reuse as P

  // packed P-writes: lane holds 4 CONSECUTIVE k per nt -> one 8B write each
  for (int nt = 0; nt < 16; ++nt) {
    *(uint2*)(k_s + (w * 16 + lr) * P_STRIDE + nt * 16 + lq * 4) =
        make_uint2(pk2bf(sc[nt][0], sc[nt][1]), pk2bf(sc[nt][2], sc[nt][3]));
  }

  f32x4 o[4];
  for (int i = 0; i < 4; ++i) o[i] = (f32x4){0.f, 0.f, 0.f, 0.f};
  bf16x8 vbuf[4];
#pragma unroll
  for (int ks = 0; ks < 8; ks += 2) {
#pragma unroll
    for (int nt2 = 0; nt2 < 4; ++nt2)
      vbuf[nt2] = *(const bf16x8*)(vbase + (size_t)(nt2 * 16 + lr) * 256 + (ks + 1) * 32 + lq * 8);
    bf16x8 pa = ld_frag8(k_s + (w * 16 + lr) * P_STRIDE + ks * 32 + lq * 8);
    __builtin_amdgcn_s_setprio(1);
#pragma unroll
    for (int nt2 = 0; nt2 < 4; ++nt2)
      o[nt2] = __builtin_amdgcn_mfma_f32_16x16x32_bf16(pa, va[nt2], o[nt2], 0, 0, 0);
    __builtin_amdgcn_s_setprio(0);
    if (ks + 2 < 8) {
#pragma unroll
      for (int nt2 = 0; nt2 < 4; ++nt2)
        va[nt2] = *(const bf16x8*)(vbase + (size_t)(nt2 * 16 + lr) * 256 + (ks + 2) * 32 + lq * 8);
    }
    bf16x8 pb = ld_frag8(k_s + (w * 16 + lr) * P_STRIDE + (ks + 1) * 32 + lq * 8);
    __builtin_amdgcn_s_setprio(1);
#pragma unroll
    for (int nt2 = 0; nt2 < 4; ++nt2)
      o[nt2] = __builtin_amdgcn_mfma_f32_16x16x32_bf16(pb, vbuf[nt2], o[nt2], 0, 0, 0);
    __builtin_amdgcn_s_setprio(0);
  }

  for (int r = 0; r < 4; ++r) {
    int strip = w * 16 + lq * 4 + r;
    int trow = cc * 64 + strip;
    float sv = __shfl(s, lq * 4 + r, 16);  // row-sum for q = w*16+lq*4+r
    if (trow < 1985) {
      size_t orow = (size_t)b * SEQ + trow + 63;
      float inv = 1.0f / sv;
      for (int nt2 = 0; nt2 < 4; ++nt2)
        out[orow * HD + hcol + nt2 * 16 + lr] = o[nt2][r] * inv;
    }
  }
}

extern "C" void kernel_launch(void* const* d_in, const int* in_sizes, int n_in,
                              void* d_out, int out_size, void* d_ws, size_t ws_size,
                              hipStream_t stream) {
  (void)in_sizes; (void)n_in; (void)out_size;
  const float* query = (const float*)d_in[0];
  const float* kv    = (const float*)d_in[1];
  const float* Wq    = (const float*)d_in[2];
  const float* bq    = (const float*)d_in[3];
  const float* Wk    = (const float*)d_in[4];
  const float* bk    = (const float*)d_in[5];
  const float* Wv    = (const float*)d_in[6];
  const float* bv    = (const float*)d_in[7];
  float* out = (float*)d_out;

  unsigned short* Qp  = (unsigned short*)d_ws;          // 8192x1024
  unsigned short* Kp  = Qp + (size_t)8192 * 1024;       // 32768x1024
  unsigned short* Vt  = Kp + (size_t)32768 * 1024;      // 32768x1024 (transposed layout)
  unsigned short* Qbf = Vt + (size_t)32768 * 1024;      // 8192x1024
  unsigned short* KVb = Qbf + (size_t)8192 * 1024;      // 32768x1024
  unsigned short* Wqb = KVb + (size_t)32768 * 1024;     // 1024x1024 x3 (contiguous)
  const size_t need = ((size_t)8192 * 1024 * 2 + (size_t)32768 * 1024 * 2 + (size_t)1024 * 1024 * 3) * 2;
  const bool big = ws_size >= need;

  if (big) {
    prep_all_kernel<<<dim3(22268), dim3(256), 0, stream>>>(query, kv, Wq, Wk, Wv,
                                                           Qbf, KVb, Wqb, out);
    gemm_all_kernel<<<dim3(8, 320), dim3(256), 0, stream>>>(Qbf, KVb, Wqb, bq, bk, bv,
                                                            Qp, Kp, Vt);
  } else {
    zero_head_kernel<<<dim3(252), dim3(256), 0, stream>>>(out);
    gemm_f32_kernel<<<dim3(8, 64), dim3(256), 0, stream>>>(query, Wq, bq, Qp, 0, 1);
    gemm_f32_kernel<<<dim3(8, 256), dim3(256), 0, stream>>>(kv, Wk, bk, Kp, 0, 0);
    gemm_f32_kernel<<<dim3(8, 256), dim3(256), 0, stream>>>(kv, Wv, bv, Vt, 1, 0);
  }
  attn_kernel<<<dim3(2048), dim3(256), 0, stream>>>(Qp, Kp, Vt, out);
}